// Round 9
// baseline (213.208 us; speedup 1.0000x reference)
//
#include <hip/hip_runtime.h>
#include <hip/hip_fp16.h>

#define NN 50000
#define NE 800000
#define CAP 64        // ELL slots per node
#define CSTR 32       // cnt stride in ints: one counter per 128B line
#define SLICE 6250    // NN / 8 nodes per XCD slice

typedef unsigned int   u32;
typedef unsigned short u16;
typedef __attribute__((ext_vector_type(8))) short short8;  // 8 bf16 in 4 VGPRs
typedef __attribute__((ext_vector_type(4))) float f32x4;

__device__ inline u16 f2bf(float f) {
    u32 u = __float_as_uint(f);
    return (u16)((u + 0x7FFF + ((u >> 16) & 1)) >> 16);   // RNE
}
__device__ inline float bfval(u16 h) { return __uint_as_float(((u32)h) << 16); }
__device__ inline float bf_lo(u32 u) { return __uint_as_float(u << 16); }
__device__ inline float bf_hi(u32 u) { return __uint_as_float(u & 0xFFFF0000u); }

// ---------------- graph build: line-isolated counters ----------------------
// cnt[d*CSTR]: one counter per 128B L2 line -> same-line atomic chains drop
// from ~256 (16 counters/line x 16 atomics) to ~16; distinct lines pipeline
// across L2 channels. XCD slicing kept for ELL write locality.

__global__ __launch_bounds__(256) void build_ell(const int* __restrict__ ei,
                                                 int* __restrict__ cnt,
                                                 u16* __restrict__ ell) {
    const int s = blockIdx.x & 7;
    const int g = blockIdx.x >> 3;            // 0..199 within slice group
    const int u = g * 256 + (int)threadIdx.x; // 0..51199
    const int lo = s * SLICE, hi = lo + SLICE;

    int dv[16], sv[16];
#pragma unroll
    for (int k = 0; k < 4; ++k) {
        int e0 = (u + k * 51200) * 4;         // coalesced: lanes contiguous
        if (e0 < NE) {                        // NE % 4 == 0
            *(int4*)&dv[k * 4] = *(const int4*)(ei + NE + e0);
            *(int4*)&sv[k * 4] = *(const int4*)(ei + e0);
        } else {
#pragma unroll
            for (int j = 0; j < 4; ++j) { dv[k * 4 + j] = -1; sv[k * 4 + j] = 0; }
        }
    }

    int pos[16];
#pragma unroll
    for (int k = 0; k < 16; ++k) {
        pos[k] = -1;
        if (dv[k] >= lo && dv[k] < hi)
            pos[k] = atomicAdd(&cnt[(size_t)dv[k] * CSTR], 1);
    }
#pragma unroll
    for (int k = 0; k < 16; ++k)
        if (pos[k] >= 0 && pos[k] < CAP)
            ell[(size_t)dv[k] * CAP + pos[k]] = (u16)sv[k];
}

// ---------------- W pre-swizzle + counter zeroing ----------------

__global__ __launch_bounds__(256) void prep_w(const float* __restrict__ W1,
                                              const float* __restrict__ W2,
                                              u16* __restrict__ W1h, u16* __restrict__ W1l,
                                              u16* __restrict__ W2h, u16* __restrict__ W2l,
                                              int* __restrict__ cnt) {
    int i = blockIdx.x * 256 + threadIdx.x;           // grid 128 -> 32768 threads
    int4* c4 = (int4*)cnt;                            // NN*CSTR ints = 400000 int4
    const int4 z = make_int4(0, 0, 0, 0);
    for (int v = i; v < NN * CSTR / 4; v += 32768) c4[v] = z;
    const float* W; u16 *Dh, *Dl; int NOUT, idx;
    if (i < 16384) { W = W1; Dh = W1h; Dl = W1l; NOUT = 128; idx = i; }
    else           { idx = i - 16384; if (idx >= 8192) return;
                     W = W2; Dh = W2h; Dl = W2l; NOUT = 64; }
    int j = idx & 7, l = (idx >> 3) & 63, kc = (idx >> 9) & 3, t = idx >> 11;
    int k = kc * 32 + (l >> 4) * 8 + j;
    int n = t * 16 + (l & 15);
    float w = W[k * NOUT + n];
    u16 h = f2bf(w);
    Dh[idx] = h;
    Dl[idx] = f2bf(w - bfval(h));
}

// ---------------- edge packing: (src u16 | fp16 norm), + degm ---------------
// Slot [0,ne) = edges, slot ne = self-loop (src=node, norm=di^2).
// degm[node] = ne+1.

__global__ __launch_bounds__(256) void pack_edges(const u16* __restrict__ ell,
                                                  const int* __restrict__ cnt,
                                                  u32* __restrict__ epk,
                                                  u16* __restrict__ degm) {
    const int tid = threadIdx.x;
    const int node = blockIdx.x * 4 + (tid >> 6);
    if (node >= NN) return;
    const int lane = tid & 63;
    const int cr = cnt[(size_t)node * CSTR];
    const int ne = min(cr, 63);
    const float di = rsqrtf((float)(cr + 1));
    if (lane == 0) degm[node] = (u16)(ne + 1);
    if (lane > ne) return;
    int s; float nr;
    if (lane < ne) {
        s = (int)ell[(size_t)node * CAP + lane];
        nr = rsqrtf((float)(cnt[(size_t)s * CSTR] + 1)) * di;
    } else { s = node; nr = di * di; }
    epk[(size_t)node * CAP + lane] =
        (u32)s | ((u32)__half_as_ushort(__float2half_rn(nr)) << 16);
}

// ---------------- MFMA GEMM1, K=128, fp32 A, 3-term bf16 split --------------

__global__ __launch_bounds__(256) void gemm1(const float* __restrict__ A,
                                             const u16* __restrict__ Wh,
                                             const u16* __restrict__ Wl,
                                             u16* __restrict__ C) {
    const int tid = threadIdx.x;
    const int w = tid >> 6, l = tid & 63;
    const int m = l & 15, q = l >> 4;

    int arow = blockIdx.x * 64 + w * 16 + m;
    const float* Ar = A + (size_t)min(arow, NN - 1) * 128;

    f32x4 acc[8] = {};
#pragma unroll
    for (int kc = 0; kc < 4; ++kc) {
        float p[8];
        *(float4*)&p[0] = *(const float4*)(Ar + kc * 32 + q * 8);
        *(float4*)&p[4] = *(const float4*)(Ar + kc * 32 + q * 8 + 4);
        short8 ah, al;
#pragma unroll
        for (int j = 0; j < 8; ++j) {
            u16 h = f2bf(p[j]);
            ah[j] = (short)h;
            al[j] = (short)f2bf(p[j] - bfval(h));
        }
#pragma unroll
        for (int t2 = 0; t2 < 8; ++t2) {
            size_t bo = ((size_t)(t2 * 4 + kc) * 64 + l) * 8;
            short8 bh = *(const short8*)(Wh + bo);
            short8 bl = *(const short8*)(Wl + bo);
            acc[t2] = __builtin_amdgcn_mfma_f32_16x16x32_bf16(ah, bh, acc[t2], 0, 0, 0);
            acc[t2] = __builtin_amdgcn_mfma_f32_16x16x32_bf16(al, bh, acc[t2], 0, 0, 0);
            acc[t2] = __builtin_amdgcn_mfma_f32_16x16x32_bf16(ah, bl, acc[t2], 0, 0, 0);
        }
    }
    int growbase = blockIdx.x * 64 + w * 16 + q * 4;
#pragma unroll
    for (int t2 = 0; t2 < 8; ++t2)
#pragma unroll
        for (int r = 0; r < 4; ++r) {
            int grow = growbase + r;
            if (grow < NN) C[(size_t)grow * 128 + t2 * 16 + m] = f2bf(acc[t2][r]);
        }
}

// ---------------- MFMA GEMM2, bf16 A exact (2-term), NOUT=64 ----------------

__global__ __launch_bounds__(256) void gemm2(const u16* __restrict__ A,
                                             const u16* __restrict__ Wh,
                                             const u16* __restrict__ Wl,
                                             u16* __restrict__ C) {
    const int tid = threadIdx.x;
    const int w = tid >> 6, l = tid & 63;
    const int m = l & 15, q = l >> 4;

    int arow = min(blockIdx.x * 64 + w * 16 + m, NN - 1);
    const u16* Ar = A + (size_t)arow * 128;

    f32x4 acc[4] = {};
#pragma unroll
    for (int kc = 0; kc < 4; ++kc) {
        short8 ah = *(const short8*)(Ar + kc * 32 + q * 8);
#pragma unroll
        for (int t2 = 0; t2 < 4; ++t2) {
            size_t bo = ((size_t)(t2 * 4 + kc) * 64 + l) * 8;
            short8 bh = *(const short8*)(Wh + bo);
            short8 bl = *(const short8*)(Wl + bo);
            acc[t2] = __builtin_amdgcn_mfma_f32_16x16x32_bf16(ah, bh, acc[t2], 0, 0, 0);
            acc[t2] = __builtin_amdgcn_mfma_f32_16x16x32_bf16(ah, bl, acc[t2], 0, 0, 0);
        }
    }
    int growbase = blockIdx.x * 64 + w * 16 + q * 4;
#pragma unroll
    for (int t2 = 0; t2 < 4; ++t2)
#pragma unroll
        for (int r = 0; r < 4; ++r) {
            int grow = growbase + r;
            if (grow < NN) C[(size_t)grow * 64 + t2 * 16 + m] = f2bf(acc[t2][r]);
        }
}

// ---------------- normalized aggregation (one wave per node, bf16 H) --------

template <int F, bool RELU, bool OUTBF>
__global__ __launch_bounds__(256) void aggregate(const u16* __restrict__ H,
                                                 const u32* __restrict__ epk,
                                                 const u16* __restrict__ degm,
                                                 const float* __restrict__ bias,
                                                 void* __restrict__ outp) {
    const int tid = threadIdx.x;
    const int node = (int)((blockIdx.x * 256 + tid) >> 6);
    if (node >= NN) return;
    const int lane = tid & 63;

    const int m = (int)degm[node];             // ne + 1 (self-loop included)
    u32 e = (lane < m) ? epk[(size_t)node * CAP + lane] : (u32)node;
    int   s_l = (int)(e & 0xFFFF);
    float n_l = (lane < m)
                    ? __half2float(__ushort_as_half((u16)(e >> 16)))
                    : 0.0f;

    constexpr int G = (F == 128) ? 4 : 8;  // edges gathered per step
    constexpr int L = 64 / G;              // lanes per edge (16B each)
    const int g = lane / L;
    const int ci = lane & (L - 1);

    const int mPad = (m + 2 * G - 1) & ~(2 * G - 1);

    float acc[8] = {0, 0, 0, 0, 0, 0, 0, 0};
    for (int j = 0; j < mPad; j += 2 * G) {
        int   sA = __shfl(s_l, j + g);
        float nA = __shfl(n_l, j + g);
        int   sB = __shfl(s_l, j + G + g);
        float nB = __shfl(n_l, j + G + g);
        uint4 vA = *(const uint4*)(H + (size_t)sA * F + ci * 8);
        uint4 vB = *(const uint4*)(H + (size_t)sB * F + ci * 8);
        acc[0] += nA * bf_lo(vA.x); acc[1] += nA * bf_hi(vA.x);
        acc[2] += nA * bf_lo(vA.y); acc[3] += nA * bf_hi(vA.y);
        acc[4] += nA * bf_lo(vA.z); acc[5] += nA * bf_hi(vA.z);
        acc[6] += nA * bf_lo(vA.w); acc[7] += nA * bf_hi(vA.w);
        acc[0] += nB * bf_lo(vB.x); acc[1] += nB * bf_hi(vB.x);
        acc[2] += nB * bf_lo(vB.y); acc[3] += nB * bf_hi(vB.y);
        acc[4] += nB * bf_lo(vB.z); acc[5] += nB * bf_hi(vB.z);
        acc[6] += nB * bf_lo(vB.w); acc[7] += nB * bf_hi(vB.w);
    }

#pragma unroll
    for (int i = 0; i < 8; ++i) {
        if (F == 64) acc[i] += __shfl_xor(acc[i], 8);
        acc[i] += __shfl_xor(acc[i], 16);
        acc[i] += __shfl_xor(acc[i], 32);
    }

    const int active = (F == 128) ? 32 : 16;
    if (lane < active) {
        int part, c0i;
        if (F == 128) { part = lane >> 4;       c0i = (lane & 15) * 8 + part * 4; }
        else          { part = (lane >> 3) & 1; c0i = (lane & 7) * 8 + part * 4; }
        float4 b4 = *(const float4*)(bias + c0i);
        float4 o = make_float4(acc[part * 4 + 0] + b4.x, acc[part * 4 + 1] + b4.y,
                               acc[part * 4 + 2] + b4.z, acc[part * 4 + 3] + b4.w);
        if (RELU) { o.x = fmaxf(o.x, 0.f); o.y = fmaxf(o.y, 0.f);
                    o.z = fmaxf(o.z, 0.f); o.w = fmaxf(o.w, 0.f); }
        if (OUTBF) {
            u16* out = (u16*)outp;
            *(ushort4*)(out + (size_t)node * F + c0i) =
                make_ushort4(f2bf(o.x), f2bf(o.y), f2bf(o.z), f2bf(o.w));
        } else {
            float* out = (float*)outp;
            *(float4*)(out + (size_t)node * F + c0i) = o;
        }
    }
}

// ---------------- launch ----------------

extern "C" void kernel_launch(void* const* d_in, const int* in_sizes, int n_in,
                              void* d_out, int out_size, void* d_ws, size_t ws_size,
                              hipStream_t stream) {
    const float* x  = (const float*)d_in[0];
    const int*   ei = (const int*)d_in[1];
    const float* W1 = (const float*)d_in[2];
    const float* b1 = (const float*)d_in[3];
    const float* W2 = (const float*)d_in[4];
    const float* b2 = (const float*)d_in[5];
    float* out = (float*)d_out;

    char* ws = (char*)d_ws;
    size_t off = 0;
    int* cnt = (int*)ws;                     off += (size_t)NN * CSTR * 4;  // 6.4 MB
    u16* ell = (u16*)(ws + off);             off += (size_t)NN * CAP * 2;
    off = (off + 255) & ~(size_t)255;
    u32* epk = (u32*)(ws + off);             off += (size_t)NN * CAP * 4;
    u16* degm = (u16*)(ws + off);            off += (size_t)NN * 2;
    off = (off + 255) & ~(size_t)255;
    u16* W1h = (u16*)(ws + off);             off += 16384 * 2;
    u16* W1l = (u16*)(ws + off);             off += 16384 * 2;
    u16* W2h = (u16*)(ws + off);             off += 8192 * 2;
    u16* W2l = (u16*)(ws + off);             off += 8192 * 2;
    off = (off + 255) & ~(size_t)255;
    u16* Hbf = (u16*)(ws + off);             off += (size_t)NN * 128 * 2;  // H1 / H2
    u16* Abf = (u16*)(ws + off);             off += (size_t)NN * 128 * 2;  // agg1 out

    prep_w<<<128, 256, 0, stream>>>(W1, W2, W1h, W1l, W2h, W2l, cnt);
    build_ell<<<1600, 256, 0, stream>>>(ei, cnt, ell);
    pack_edges<<<12500, 256, 0, stream>>>(ell, cnt, epk, degm);

    // layer 1: H1 = x@W1 (bf16) ; agg+bias+relu -> Abf (bf16)
    gemm1<<<(NN + 63) / 64, 256, 0, stream>>>(x, W1h, W1l, Hbf);
    aggregate<128, true, true><<<(NN + 3) / 4, 256, 0, stream>>>(Hbf, epk, degm, b1, Abf);

    // layer 2: H2 = Abf@W2 (bf16 A exact) ; agg+bias -> out (fp32)
    gemm2<<<(NN + 63) / 64, 256, 0, stream>>>(Abf, W2h, W2l, Hbf);
    aggregate<64, false, false><<<(NN + 3) / 4, 256, 0, stream>>>(Hbf, epk, degm, b2, out);
}

// Round 10
// 196.940 us; speedup vs baseline: 1.0826x; 1.0826x over previous
//
#include <hip/hip_runtime.h>
#include <hip/hip_fp16.h>

#define NN 50000
#define NE 800000
#define CAP 64        // ELL slots per node
#define CSTR 32       // cnt stride in ints: one counter per 128B line
#define SLICE 6250    // NN / 8 nodes per XCD slice
#define GT1 782       // gemm1 tiles = ceil(NN/64); K1 blocks [0,GT1) do gemm1

typedef unsigned int   u32;
typedef unsigned short u16;
typedef __attribute__((ext_vector_type(8))) short short8;  // 8 bf16 in 4 VGPRs
typedef __attribute__((ext_vector_type(4))) float f32x4;

__device__ inline u16 f2bf(float f) {
    u32 u = __float_as_uint(f);
    return (u16)((u + 0x7FFF + ((u >> 16) & 1)) >> 16);   // RNE
}
__device__ inline float bfval(u16 h) { return __uint_as_float(((u32)h) << 16); }
__device__ inline float bf_lo(u32 u) { return __uint_as_float(u << 16); }
__device__ inline float bf_hi(u32 u) { return __uint_as_float(u & 0xFFFF0000u); }

// ---------------- K0: W pre-swizzle + counter zeroing ----------------

__global__ __launch_bounds__(256) void prep_w(const float* __restrict__ W1,
                                              const float* __restrict__ W2,
                                              u16* __restrict__ W1h, u16* __restrict__ W1l,
                                              u16* __restrict__ W2h, u16* __restrict__ W2l,
                                              int* __restrict__ cnt) {
    int i = blockIdx.x * 256 + threadIdx.x;           // grid 128 -> 32768 threads
    int4* c4 = (int4*)cnt;                            // NN*CSTR ints = 400000 int4
    const int4 z = make_int4(0, 0, 0, 0);
    for (int v = i; v < NN * CSTR / 4; v += 32768) c4[v] = z;
    const float* W; u16 *Dh, *Dl; int NOUT, idx;
    if (i < 16384) { W = W1; Dh = W1h; Dl = W1l; NOUT = 128; idx = i; }
    else           { idx = i - 16384; if (idx >= 8192) return;
                     W = W2; Dh = W2h; Dl = W2l; NOUT = 64; }
    int j = idx & 7, l = (idx >> 3) & 63, kc = (idx >> 9) & 3, t = idx >> 11;
    int k = kc * 32 + (l >> 4) * 8 + j;
    int n = t * 16 + (l & 15);
    float w = W[k * NOUT + n];
    u16 h = f2bf(w);
    Dh[idx] = h;
    Dl[idx] = f2bf(w - bfval(h));
}

// ---------------- K1: build_ell (blocks >= GT1) || gemm1 (blocks < GT1) -----
// Independent workloads, no sync needed: consumers are in later launches.
// Build is r9's (XCD-sliced, line-isolated counters); gemm1 is the 3-term
// bf16-split MFMA GEMM. Latency-bound build + MFMA-bound gemm co-schedule.

__device__ void dev_build(int b, int tid, const int* __restrict__ ei,
                          int* __restrict__ cnt, u16* __restrict__ ell) {
    const int s = b & 7;
    const int g = b >> 3;                     // 0..199 within slice group
    const int u = g * 256 + tid;              // 0..51199
    const int lo = s * SLICE, hi = lo + SLICE;

    int dv[16], sv[16];
#pragma unroll
    for (int k = 0; k < 4; ++k) {
        int e0 = (u + k * 51200) * 4;         // coalesced: lanes contiguous
        if (e0 < NE) {
            *(int4*)&dv[k * 4] = *(const int4*)(ei + NE + e0);
            *(int4*)&sv[k * 4] = *(const int4*)(ei + e0);
        } else {
#pragma unroll
            for (int j = 0; j < 4; ++j) { dv[k * 4 + j] = -1; sv[k * 4 + j] = 0; }
        }
    }

    int pos[16];
#pragma unroll
    for (int k = 0; k < 16; ++k) {
        pos[k] = -1;
        if (dv[k] >= lo && dv[k] < hi)
            pos[k] = atomicAdd(&cnt[(size_t)dv[k] * CSTR], 1);
    }
#pragma unroll
    for (int k = 0; k < 16; ++k)
        if (pos[k] >= 0 && pos[k] < CAP)
            ell[(size_t)dv[k] * CAP + pos[k]] = (u16)sv[k];
}

__device__ void dev_gemm1(int tile, int tid, const float* __restrict__ A,
                          const u16* __restrict__ Wh, const u16* __restrict__ Wl,
                          u16* __restrict__ C) {
    const int w = tid >> 6, l = tid & 63;
    const int m = l & 15, q = l >> 4;

    int arow = tile * 64 + w * 16 + m;
    const float* Ar = A + (size_t)min(arow, NN - 1) * 128;

    f32x4 acc[8] = {};
#pragma unroll
    for (int kc = 0; kc < 4; ++kc) {
        float p[8];
        *(float4*)&p[0] = *(const float4*)(Ar + kc * 32 + q * 8);
        *(float4*)&p[4] = *(const float4*)(Ar + kc * 32 + q * 8 + 4);
        short8 ah, al;
#pragma unroll
        for (int j = 0; j < 8; ++j) {
            u16 h = f2bf(p[j]);
            ah[j] = (short)h;
            al[j] = (short)f2bf(p[j] - bfval(h));
        }
#pragma unroll
        for (int t2 = 0; t2 < 8; ++t2) {
            size_t bo = ((size_t)(t2 * 4 + kc) * 64 + l) * 8;
            short8 bh = *(const short8*)(Wh + bo);
            short8 bl = *(const short8*)(Wl + bo);
            acc[t2] = __builtin_amdgcn_mfma_f32_16x16x32_bf16(ah, bh, acc[t2], 0, 0, 0);
            acc[t2] = __builtin_amdgcn_mfma_f32_16x16x32_bf16(al, bh, acc[t2], 0, 0, 0);
            acc[t2] = __builtin_amdgcn_mfma_f32_16x16x32_bf16(ah, bl, acc[t2], 0, 0, 0);
        }
    }
    int growbase = tile * 64 + w * 16 + q * 4;
#pragma unroll
    for (int t2 = 0; t2 < 8; ++t2)
#pragma unroll
        for (int r = 0; r < 4; ++r) {
            int grow = growbase + r;
            if (grow < NN) C[(size_t)grow * 128 + t2 * 16 + m] = f2bf(acc[t2][r]);
        }
}

__global__ __launch_bounds__(256) void k_build_gemm1(const int* __restrict__ ei,
                                                     int* __restrict__ cnt,
                                                     u16* __restrict__ ell,
                                                     const float* __restrict__ x,
                                                     const u16* __restrict__ W1h,
                                                     const u16* __restrict__ W1l,
                                                     u16* __restrict__ Hbf) {
    const int b = blockIdx.x, tid = threadIdx.x;
    if (b < GT1) dev_gemm1(b, tid, x, W1h, W1l, Hbf);
    else         dev_build(b - GT1, tid, ei, cnt, ell);
}

// ---------------- K2: agg1 fused with edge packing --------------------------
// One wave per node. Computes (src, norm) inline from ell/cnt (no epk read),
// writes epk (fp16 norm) + degm as a side product for agg2, then does the
// G=4-edges x 16-lane x 16B gather/accumulate. bias+relu, bf16 out.

__global__ __launch_bounds__(256) void agg1_pack(const u16* __restrict__ H,
                                                 const u16* __restrict__ ell,
                                                 const int* __restrict__ cnt,
                                                 u32* __restrict__ epk,
                                                 u16* __restrict__ degm,
                                                 const float* __restrict__ bias,
                                                 u16* __restrict__ outp) {
    const int tid = threadIdx.x;
    const int node = (int)((blockIdx.x * 256 + tid) >> 6);
    if (node >= NN) return;
    const int lane = tid & 63;

    const int cr = cnt[(size_t)node * CSTR];
    const int ne = min(cr, 63);
    const int m = ne + 1;
    const float di = rsqrtf((float)(cr + 1));
    if (lane == 0) degm[node] = (u16)m;

    int s_l; float n_l;
    if (lane < ne) {
        s_l = (int)ell[(size_t)node * CAP + lane];
        n_l = rsqrtf((float)(cnt[(size_t)s_l * CSTR] + 1)) * di;
    } else if (lane == ne) { s_l = node; n_l = di * di; }
    else                   { s_l = node; n_l = 0.0f; }
    if (lane < m)
        epk[(size_t)node * CAP + lane] =
            (u32)s_l | ((u32)__half_as_ushort(__float2half_rn(n_l)) << 16);

    const int g = lane >> 4;               // G=4 edge groups
    const int ci = lane & 15;              // 16 lanes x 16B = 256B row
    const int mPad = (m + 7) & ~7;

    float acc[8] = {0, 0, 0, 0, 0, 0, 0, 0};
    for (int j = 0; j < mPad; j += 8) {
        int   sA = __shfl(s_l, j + g);
        float nA = __shfl(n_l, j + g);
        int   sB = __shfl(s_l, j + 4 + g);
        float nB = __shfl(n_l, j + 4 + g);
        uint4 vA = *(const uint4*)(H + (size_t)sA * 128 + ci * 8);
        uint4 vB = *(const uint4*)(H + (size_t)sB * 128 + ci * 8);
        acc[0] += nA * bf_lo(vA.x); acc[1] += nA * bf_hi(vA.x);
        acc[2] += nA * bf_lo(vA.y); acc[3] += nA * bf_hi(vA.y);
        acc[4] += nA * bf_lo(vA.z); acc[5] += nA * bf_hi(vA.z);
        acc[6] += nA * bf_lo(vA.w); acc[7] += nA * bf_hi(vA.w);
        acc[0] += nB * bf_lo(vB.x); acc[1] += nB * bf_hi(vB.x);
        acc[2] += nB * bf_lo(vB.y); acc[3] += nB * bf_hi(vB.y);
        acc[4] += nB * bf_lo(vB.z); acc[5] += nB * bf_hi(vB.z);
        acc[6] += nB * bf_lo(vB.w); acc[7] += nB * bf_hi(vB.w);
    }

#pragma unroll
    for (int i = 0; i < 8; ++i) {
        acc[i] += __shfl_xor(acc[i], 16);
        acc[i] += __shfl_xor(acc[i], 32);
    }

    if (lane < 32) {
        int part = lane >> 4;
        int c0i = (lane & 15) * 8 + part * 4;
        float4 b4 = *(const float4*)(bias + c0i);
        float4 o = make_float4(acc[part * 4 + 0] + b4.x, acc[part * 4 + 1] + b4.y,
                               acc[part * 4 + 2] + b4.z, acc[part * 4 + 3] + b4.w);
        o.x = fmaxf(o.x, 0.f); o.y = fmaxf(o.y, 0.f);
        o.z = fmaxf(o.z, 0.f); o.w = fmaxf(o.w, 0.f);
        *(ushort4*)(outp + (size_t)node * 128 + c0i) =
            make_ushort4(f2bf(o.x), f2bf(o.y), f2bf(o.z), f2bf(o.w));
    }
}

// ---------------- K3: MFMA GEMM2, bf16 A exact (2-term), NOUT=64 ------------

__global__ __launch_bounds__(256) void gemm2(const u16* __restrict__ A,
                                             const u16* __restrict__ Wh,
                                             const u16* __restrict__ Wl,
                                             u16* __restrict__ C) {
    const int tid = threadIdx.x;
    const int w = tid >> 6, l = tid & 63;
    const int m = l & 15, q = l >> 4;

    int arow = min(blockIdx.x * 64 + w * 16 + m, NN - 1);
    const u16* Ar = A + (size_t)arow * 128;

    f32x4 acc[4] = {};
#pragma unroll
    for (int kc = 0; kc < 4; ++kc) {
        short8 ah = *(const short8*)(Ar + kc * 32 + q * 8);
#pragma unroll
        for (int t2 = 0; t2 < 4; ++t2) {
            size_t bo = ((size_t)(t2 * 4 + kc) * 64 + l) * 8;
            short8 bh = *(const short8*)(Wh + bo);
            short8 bl = *(const short8*)(Wl + bo);
            acc[t2] = __builtin_amdgcn_mfma_f32_16x16x32_bf16(ah, bh, acc[t2], 0, 0, 0);
            acc[t2] = __builtin_amdgcn_mfma_f32_16x16x32_bf16(ah, bl, acc[t2], 0, 0, 0);
        }
    }
    int growbase = blockIdx.x * 64 + w * 16 + q * 4;
#pragma unroll
    for (int t2 = 0; t2 < 4; ++t2)
#pragma unroll
        for (int r = 0; r < 4; ++r) {
            int grow = growbase + r;
            if (grow < NN) C[(size_t)grow * 64 + t2 * 16 + m] = f2bf(acc[t2][r]);
        }
}

// ---------------- K4: agg2 (reads epk/degm), bias, fp32 out -----------------

__global__ __launch_bounds__(256) void agg2(const u16* __restrict__ H,
                                            const u32* __restrict__ epk,
                                            const u16* __restrict__ degm,
                                            const float* __restrict__ bias,
                                            float* __restrict__ outp) {
    const int tid = threadIdx.x;
    const int node = (int)((blockIdx.x * 256 + tid) >> 6);
    if (node >= NN) return;
    const int lane = tid & 63;

    const int m = (int)degm[node];             // ne + 1 (self-loop included)
    u32 e = (lane < m) ? epk[(size_t)node * CAP + lane] : (u32)node;
    int   s_l = (int)(e & 0xFFFF);
    float n_l = (lane < m)
                    ? __half2float(__ushort_as_half((u16)(e >> 16)))
                    : 0.0f;

    const int g = lane >> 3;               // G=8 edge groups
    const int ci = lane & 7;               // 8 lanes x 16B = 128B row
    const int mPad = (m + 15) & ~15;

    float acc[8] = {0, 0, 0, 0, 0, 0, 0, 0};
    for (int j = 0; j < mPad; j += 16) {
        int   sA = __shfl(s_l, j + g);
        float nA = __shfl(n_l, j + g);
        int   sB = __shfl(s_l, j + 8 + g);
        float nB = __shfl(n_l, j + 8 + g);
        uint4 vA = *(const uint4*)(H + (size_t)sA * 64 + ci * 8);
        uint4 vB = *(const uint4*)(H + (size_t)sB * 64 + ci * 8);
        acc[0] += nA * bf_lo(vA.x); acc[1] += nA * bf_hi(vA.x);
        acc[2] += nA * bf_lo(vA.y); acc[3] += nA * bf_hi(vA.y);
        acc[4] += nA * bf_lo(vA.z); acc[5] += nA * bf_hi(vA.z);
        acc[6] += nA * bf_lo(vA.w); acc[7] += nA * bf_hi(vA.w);
        acc[0] += nB * bf_lo(vB.x); acc[1] += nB * bf_hi(vB.x);
        acc[2] += nB * bf_lo(vB.y); acc[3] += nB * bf_hi(vB.y);
        acc[4] += nB * bf_lo(vB.z); acc[5] += nB * bf_hi(vB.z);
        acc[6] += nB * bf_lo(vB.w); acc[7] += nB * bf_hi(vB.w);
    }

#pragma unroll
    for (int i = 0; i < 8; ++i) {
        acc[i] += __shfl_xor(acc[i], 8);
        acc[i] += __shfl_xor(acc[i], 16);
        acc[i] += __shfl_xor(acc[i], 32);
    }

    if (lane < 16) {
        int part = (lane >> 3) & 1;
        int c0i = (lane & 7) * 8 + part * 4;
        float4 b4 = *(const float4*)(bias + c0i);
        float4 o = make_float4(acc[part * 4 + 0] + b4.x, acc[part * 4 + 1] + b4.y,
                               acc[part * 4 + 2] + b4.z, acc[part * 4 + 3] + b4.w);
        *(float4*)(outp + (size_t)node * 64 + c0i) = o;
    }
}

// ---------------- launch ----------------

extern "C" void kernel_launch(void* const* d_in, const int* in_sizes, int n_in,
                              void* d_out, int out_size, void* d_ws, size_t ws_size,
                              hipStream_t stream) {
    const float* x  = (const float*)d_in[0];
    const int*   ei = (const int*)d_in[1];
    const float* W1 = (const float*)d_in[2];
    const float* b1 = (const float*)d_in[3];
    const float* W2 = (const float*)d_in[4];
    const float* b2 = (const float*)d_in[5];
    float* out = (float*)d_out;

    char* ws = (char*)d_ws;
    size_t off = 0;
    int* cnt = (int*)ws;                     off += (size_t)NN * CSTR * 4;  // 6.4 MB
    u16* ell = (u16*)(ws + off);             off += (size_t)NN * CAP * 2;
    off = (off + 255) & ~(size_t)255;
    u32* epk = (u32*)(ws + off);             off += (size_t)NN * CAP * 4;
    u16* degm = (u16*)(ws + off);            off += (size_t)NN * 2;
    off = (off + 255) & ~(size_t)255;
    u16* W1h = (u16*)(ws + off);             off += 16384 * 2;
    u16* W1l = (u16*)(ws + off);             off += 16384 * 2;
    u16* W2h = (u16*)(ws + off);             off += 8192 * 2;
    u16* W2l = (u16*)(ws + off);             off += 8192 * 2;
    off = (off + 255) & ~(size_t)255;
    u16* Hbf = (u16*)(ws + off);             off += (size_t)NN * 128 * 2;  // H1 / H2
    u16* Abf = (u16*)(ws + off);             off += (size_t)NN * 128 * 2;  // agg1 out

    prep_w<<<128, 256, 0, stream>>>(W1, W2, W1h, W1l, W2h, W2l, cnt);
    k_build_gemm1<<<GT1 + 1600, 256, 0, stream>>>(ei, cnt, ell, x, W1h, W1l, Hbf);
    agg1_pack<<<(NN + 3) / 4, 256, 0, stream>>>(Hbf, ell, cnt, epk, degm, b1, Abf);
    gemm2<<<(NN + 63) / 64, 256, 0, stream>>>(Abf, W2h, W2l, Hbf);
    agg2<<<(NN + 3) / 4, 256, 0, stream>>>(Hbf, epk, degm, b2, out);
}